// Round 15
// baseline (110.982 us; speedup 1.0000x reference)
//
#include <hip/hip_runtime.h>
#include <cstdint>
#include <cstddef>

namespace {

constexpr int kB = 16;
constexpr int kH = 512;
constexpr int kW = 512;
constexpr int kHW = kH * kW;
constexpr int kNS = 37632;     // NUM_POINTS * OVERSAMPLE
constexpr int kNS4 = kNS / 4;  // 9408
constexpr int kNUNC = 9408;
constexpr int kNRAND = 3136;
constexpr int kNPTS = 12544;
constexpr int kBins = 16384;   // exp(8)+mant(6) bins of |z|
constexpr int kBXB = 16;       // bbox partial blocks per batch
constexpr int kRPB = 4;        // rand-point blocks per batch
constexpr int kSLB = 16;       // slices per batch (hist/os-CE/region)
constexpr int kSlice4 = kNS4 / kSLB;    // 588 uint4 per slice
constexpr int kPairs = kNS / 2;
constexpr int kSampSlots = 148;
constexpr int kSampleBlocks = 8 * kSampSlots;    // 1184
constexpr int kBboxBlocks = kB * kBXB;           // 256
constexpr int kRandBlocks = kB * kRPB;           // 64
constexpr int kHStride = 1025;                   // swizzled LDS hist row stride
constexpr int kCAPS = 256;                       // per-slice candidate capacity

// workspace layout (bytes)
constexpr size_t OFF_PZ   = 0;                                      // [B][NS] u32 signed z bits
constexpr size_t OFF_TV   = OFF_PZ + (size_t)kB * kNS * 4;          // [B][NS] f32 gt label
constexpr size_t OFF_PH   = OFF_TV + (size_t)kB * kNS * 4;          // [B][16][16384] u16 partial hists
constexpr size_t OFF_BBP  = OFF_PH + (size_t)kB * kSLB * kBins * 2; // [B][16][4] i32
constexpr size_t OFF_PLP  = OFF_BBP + (size_t)kB * kBXB * 4 * 4;    // [B][4][4] f32 rand partials
constexpr size_t OFF_OSP2 = OFF_PLP + (size_t)kB * kRPB * 4 * 4;    // [B][16][4] f32 os slice sums
constexpr size_t OFF_RGP  = OFF_OSP2 + (size_t)kB * kSLB * 4 * 4;   // [B][16][5] f32 region partials
constexpr size_t OFF_CAND = OFF_RGP + (size_t)kB * kSLB * 5 * 4;    // [B][16][256] i32 ordered cands
constexpr size_t OFF_SCNT = OFF_CAND + (size_t)kB * kSLB * kCAPS * 4; // [B][16] i32 real counts
constexpr size_t OFF_BNFO = OFF_SCNT + (size_t)kB * kSLB * 4;       // [B][2] i32 (bstar, need)

// Swizzled LDS hist: bin -> (bin&15)*1025 + (bin>>4).
__device__ __forceinline__ int SW(int bin) {
  return (bin & 15) * kHStride + (bin >> 4);
}

} // namespace

__device__ __forceinline__ float sample_bilinear(const float* __restrict__ img,
                                                 float cx, float cy) {
  float x = cx * (float)kW - 0.5f;
  float y = cy * (float)kH - 0.5f;
  float x0f = floorf(x), y0f = floorf(y);
  float wx1 = x - x0f, wx0 = 1.0f - wx1;
  float wy1 = y - y0f, wy0 = 1.0f - wy1;
  int x0 = (int)x0f, y0 = (int)y0f;
  int x1 = x0 + 1, y1 = y0 + 1;
  int xc0 = min(max(x0, 0), kW - 1), xc1 = min(max(x1, 0), kW - 1);
  int yc0 = min(max(y0, 0), kH - 1), yc1 = min(max(y1, 0), kH - 1);
  float v00 = ((x0 >= 0) && (x0 < kW) && (y0 >= 0) && (y0 < kH)) ? img[yc0 * kW + xc0] : 0.0f;
  float v01 = ((x1 >= 0) && (x1 < kW) && (y0 >= 0) && (y0 < kH)) ? img[yc0 * kW + xc1] : 0.0f;
  float v10 = ((x0 >= 0) && (x0 < kW) && (y1 >= 0) && (y1 < kH)) ? img[yc1 * kW + xc0] : 0.0f;
  float v11 = ((x1 >= 0) && (x1 < kW) && (y1 >= 0) && (y1 < kH)) ? img[yc1 * kW + xc1] : 0.0f;
  return v00 * (wy0 * wx0) + v01 * (wy0 * wx1) + v10 * (wy1 * wx0) + v11 * (wy1 * wx1);
}

__device__ __forceinline__ void ce_pair(float z, float tt, float& ce, float& p) {
  float a = expf(-fabsf(z));
  ce = fmaxf(z, 0.0f) - z * tt + log1pf(a);
  float inv = 1.0f / (1.0f + a);
  p = (z >= 0.0f) ? inv : a * inv;
}

// ---- K1: os sampling (pz/tv stores) | bbox | rand CE; XCD-clustered ----
__global__ __launch_bounds__(256) void fused1_kernel(const float* __restrict__ pred,
                                                     const float* __restrict__ gt,
                                                     const float* __restrict__ coords_os,
                                                     const float* __restrict__ coords_rand,
                                                     unsigned* __restrict__ pz,
                                                     float* __restrict__ tv,
                                                     int* __restrict__ bbp,
                                                     float* __restrict__ plp) {
  int blk = blockIdx.x;
  int t = threadIdx.x;

  if (blk < kSampleBlocks) {
    int x = blk & 7;
    int s = blk >> 3;                 // 0..147
    int b = x * 2 + (s & 1);          // XCD-clustered: batch b on XCD b/2
    int chunk = s >> 1;               // 0..73
    int pib = chunk * 256 + t;
    if (pib >= kPairs) return;
    size_t gp = (size_t)b * kPairs + pib;
    float4 c2 = ((const float4*)coords_os)[gp];
    size_t i0 = gp * 2;
    const float* pred_b = pred + (size_t)b * kHW;
    const float* gt_b = gt + (size_t)b * kHW;
    float z0 = sample_bilinear(pred_b, c2.x, c2.y);
    float z1 = sample_bilinear(pred_b, c2.z, c2.w);
    float t0 = sample_bilinear(gt_b, c2.x, c2.y);
    float t1 = sample_bilinear(gt_b, c2.z, c2.w);
    *(uint2*)&pz[i0] = make_uint2(__float_as_uint(z0), __float_as_uint(z1));
    *(float2*)&tv[i0] = make_float2(t0, t1);
    return;
  }

  if (blk < kSampleBlocks + kBboxBlocks) {
    __shared__ int r0[256], r1[256], r2[256], r3[256];
    int i = blk - kSampleBlocks;
    int x = i & 7;
    int s = i >> 3;                   // 0..31
    int b = x * 2 + (s & 1);
    int c = s >> 1;                   // 0..15
    constexpr int CHUNK4 = kHW / kBXB / 4;  // 4096 float4
    const float4* pred4 = (const float4*)(pred + (size_t)b * kHW) + (size_t)c * CHUNK4;
    int pbase = c * CHUNK4 * 4;
    int xmn = kW, xmx = -1, ymn = kH, ymx = -1;
    for (int i4 = t; i4 < CHUNK4; i4 += 256) {
      float4 z = pred4[i4];
      int p = pbase + i4 * 4;
      int y = p >> 9;
      int x0 = p & (kW - 1);
      if (z.x > 0.0f) { xmn = min(xmn, x0);     xmx = max(xmx, x0);     ymn = min(ymn, y); ymx = max(ymx, y); }
      if (z.y > 0.0f) { xmn = min(xmn, x0 + 1); xmx = max(xmx, x0 + 1); ymn = min(ymn, y); ymx = max(ymx, y); }
      if (z.z > 0.0f) { xmn = min(xmn, x0 + 2); xmx = max(xmx, x0 + 2); ymn = min(ymn, y); ymx = max(ymx, y); }
      if (z.w > 0.0f) { xmn = min(xmn, x0 + 3); xmx = max(xmx, x0 + 3); ymn = min(ymn, y); ymx = max(ymx, y); }
    }
    r0[t] = xmn; r1[t] = xmx; r2[t] = ymn; r3[t] = ymx;
    __syncthreads();
    for (int s2 = 128; s2 > 0; s2 >>= 1) {
      if (t < s2) {
        r0[t] = min(r0[t], r0[t + s2]);
        r1[t] = max(r1[t], r1[t + s2]);
        r2[t] = min(r2[t], r2[t + s2]);
        r3[t] = max(r3[t], r3[t + s2]);
      }
      __syncthreads();
    }
    if (t == 0) {
      int* o = bbp + ((size_t)b * kBXB + c) * 4;
      o[0] = r0[0]; o[1] = r1[0]; o[2] = r2[0]; o[3] = r3[0];
    }
    return;
  }

  // rand-point CE partials
  {
    __shared__ float red[4][256];
    int i = blk - kSampleBlocks - kBboxBlocks;
    int x = i & 7;
    int s = i >> 3;                   // 0..7
    int b = x * 2 + (s & 1);
    int c = s >> 1;                   // 0..3
    const float* pred_b = pred + (size_t)b * kHW;
    const float* gt_b = gt + (size_t)b * kHW;
    float ce_s = 0.0f, p_s = 0.0f, t_s = 0.0f, pt_s = 0.0f;
    for (int e = c * 256 + t; e < kNRAND; e += kRPB * 256) {
      float2 cc = *(const float2*)&coords_rand[((size_t)b * kNRAND + e) * 2];
      float z = sample_bilinear(pred_b, cc.x, cc.y);
      float tt = sample_bilinear(gt_b, cc.x, cc.y);
      float ce, p;
      ce_pair(z, tt, ce, p);
      ce_s += ce; p_s += p; t_s += tt; pt_s += p * tt;
    }
    red[0][t] = ce_s; red[1][t] = p_s; red[2][t] = t_s; red[3][t] = pt_s;
    __syncthreads();
    for (int s2 = 128; s2 > 0; s2 >>= 1) {
      if (t < s2) {
        red[0][t] += red[0][t + s2];
        red[1][t] += red[1][t + s2];
        red[2][t] += red[2][t + s2];
        red[3][t] += red[3][t + s2];
      }
      __syncthreads();
    }
    if (t == 0) {
      float* o = plp + ((size_t)b * kRPB + c) * 4;
      o[0] = red[0][0]; o[1] = red[1][0]; o[2] = red[2][0]; o[3] = red[3][0];
    }
  }
}

// ---- K2: 256 blocks: region chunk + SLICE partial hist (low contention) ----
__global__ __launch_bounds__(1024) void region_hist_kernel(const unsigned* __restrict__ pz,
                                                           const float* __restrict__ pred,
                                                           const float* __restrict__ gt,
                                                           const int* __restrict__ bbp,
                                                           float* __restrict__ rgp,
                                                           unsigned short* __restrict__ ph) {
  __shared__ unsigned hist[16 * kHStride];   // 65.6 KB swizzled
  __shared__ float redf[16 * 5];
  int blk = blockIdx.x;
  int t = threadIdx.x;
  int x = blk & 7;
  int s = blk >> 3;                 // 0..31
  int b = x * 2 + (s & 1);          // XCD-clustered
  int c = s >> 1;                   // 0..15 (slice)

  for (int i = t; i < 16 * kHStride; i += 1024) hist[i] = 0u;

  // ---- region chunk ----
  {
    constexpr int CHUNK4 = kHW / kSLB / 4;  // 4096 float4
    const float4* pred4 = (const float4*)(pred + (size_t)b * kHW) + (size_t)c * CHUNK4;
    const float4* gt4 = (const float4*)(gt + (size_t)b * kHW) + (size_t)c * CHUNK4;
    int xmn = kW, xmx = -1, ymn = kH, ymx = -1;
#pragma unroll
    for (int u = 0; u < kBXB; ++u) {
      const int4 pb = *(const int4*)(bbp + ((size_t)b * kBXB + u) * 4);
      xmn = min(xmn, pb.x); xmx = max(xmx, pb.y);
      ymn = min(ymn, pb.z); ymx = max(ymx, pb.w);
    }
    bool empty = (xmx < 0);
    int x1 = empty ? 0 : xmn;
    int x2 = min(empty ? (kW - 1) : xmx, kW - 1);
    int y1 = empty ? 0 : ymn;
    int y2 = min(empty ? (kH - 1) : ymx, kH - 1);
    bool valid = (x2 > x1) && (y2 > y1);

    int pbase = c * CHUNK4 * 4;
    float wsum = 0.0f, bcew = 0.0f, inter = 0.0f, pw = 0.0f, gw = 0.0f;
    for (int i4 = t; i4 < CHUNK4; i4 += 1024) {
      float4 zv = pred4[i4];
      float4 gv = gt4[i4];
      int p = pbase + i4 * 4;
      int y = p >> 9;
      int x0 = p & (kW - 1);
      bool iny = valid && (y >= y1) && (y <= y2);
#pragma unroll
      for (int l = 0; l < 4; ++l) {
        float z = (l == 0) ? zv.x : (l == 1) ? zv.y : (l == 2) ? zv.z : zv.w;
        float g = (l == 0) ? gv.x : (l == 1) ? gv.y : (l == 2) ? gv.z : gv.w;
        int xx = x0 + l;
        float w = (iny && xx >= x1 && xx <= x2) ? 2.0f : 0.5f;
        float a = expf(-fabsf(z));
        float sp = fmaxf(-z, 0.0f) + log1pf(a);
        float bce = sp + (1.0f - g) * z;
        float inv = 1.0f / (1.0f + a);
        float pp = (z >= 0.0f) ? inv : a * inv;
        wsum += w;
        bcew += bce * w;
        inter += pp * g * w;
        pw += pp * w;
        gw += g * w;
      }
    }
    float vals[5] = {wsum, bcew, inter, pw, gw};
#pragma unroll
    for (int q5 = 0; q5 < 5; ++q5) {
      float v = vals[q5];
      for (int o = 32; o > 0; o >>= 1) v += __shfl_down(v, o, 64);
      if ((t & 63) == 0) redf[(t >> 6) * 5 + q5] = v;
    }
    __syncthreads();
    if (t == 0) {
      float o0 = 0, o1 = 0, o2 = 0, o3 = 0, o4 = 0;
      for (int w = 0; w < 16; ++w) {
        o0 += redf[w * 5 + 0]; o1 += redf[w * 5 + 1]; o2 += redf[w * 5 + 2];
        o3 += redf[w * 5 + 3]; o4 += redf[w * 5 + 4];
      }
      float* o = rgp + ((size_t)b * kSLB + c) * 5;
      o[0] = o0; o[1] = o1; o[2] = o2; o[3] = o3; o[4] = o4;
    }
  }

  // ---- slice partial histogram (<=4 atomics/thread, minimal same-addr collision) ----
  {
    const uint4* pz4_b = (const uint4*)(pz + (size_t)b * kNS);
    if (t < kSlice4) {
      uint4 u = pz4_b[c * kSlice4 + t];
      atomicAdd(&hist[SW((int)((u.x & 0x7fffffffu) >> 17))], 1u);
      atomicAdd(&hist[SW((int)((u.y & 0x7fffffffu) >> 17))], 1u);
      atomicAdd(&hist[SW((int)((u.z & 0x7fffffffu) >> 17))], 1u);
      atomicAdd(&hist[SW((int)((u.w & 0x7fffffffu) >> 17))], 1u);
    }
    __syncthreads();
    // write partial hist as packed u16 pairs; word t*8+j = bins (t*16+2j, t*16+2j+1)
    unsigned* out = (unsigned*)(ph + ((size_t)b * kSLB + c) * kBins);
#pragma unroll
    for (int j = 0; j < 8; ++j) {
      unsigned lo = hist[(2 * j) * kHStride + t];
      unsigned hi = hist[(2 * j + 1) * kHStride + t];
      out[t * 8 + j] = (lo & 0xffffu) | (hi << 16);
    }
  }
}

// ---- K3: 256 blocks: redundant per-block hist combine -> bstar/need, then
//      os-CE slice + ORDERED candidate append (prefix scan) ----
__global__ __launch_bounds__(1024) void combine_osce_kernel(const unsigned* __restrict__ pz,
                                                            const float* __restrict__ tv,
                                                            const unsigned short* __restrict__ ph,
                                                            float* __restrict__ osp2,
                                                            int* __restrict__ cand,
                                                            int* __restrict__ scnt,
                                                            int* __restrict__ binfo) {
  __shared__ unsigned sums[1024];
  __shared__ unsigned scan[1024];
  __shared__ float redf[16 * 4];
  __shared__ int s_bstar, s_need;
  int blk = blockIdx.x;
  int t = threadIdx.x;
  int x = blk & 7;
  int s = blk >> 3;
  int b = x * 2 + (s & 1);          // XCD-clustered
  int c = s >> 1;

  // ---- combine 16 partial hists (L2-hot, deterministic in every block) ----
  const unsigned short* ph_b = ph + (size_t)b * kSLB * kBins;
  {
    unsigned sloc = 0;
#pragma unroll
    for (int sl = 0; sl < kSLB; ++sl) {
      const unsigned* p32 = (const unsigned*)(ph_b + (size_t)sl * kBins);
#pragma unroll
      for (int j = 0; j < 8; ++j) {
        unsigned u = p32[t * 8 + j];
        sloc += (u & 0xffffu) + (u >> 16);
      }
    }
    sums[t] = sloc;                    // total over bins [t*16, t*16+16)
    __syncthreads();
    if (t < 64) {
      const unsigned K = (unsigned)kNUNC;
      unsigned v = 0;
#pragma unroll
      for (int k = 0; k < 16; ++k) v += sums[t * 16 + k];   // bins t*256..
      unsigned cum = v;
      for (int off = 1; off < 64; off <<= 1) {
        unsigned xx = __shfl_up(cum, off, 64);
        if (t >= off) cum += xx;
      }
      unsigned long long m = __ballot(cum >= K);
      int L = (int)__ffsll(m) - 1;
      unsigned base1 = __shfl(cum - v, L, 64);
      unsigned v2 = (t < 16) ? sums[L * 16 + t] : 0u;
      unsigned cum2 = v2;
      for (int off = 1; off < 16; off <<= 1) {
        unsigned xx = __shfl_up(cum2, off, 64);
        if (t >= off) cum2 += xx;
      }
      unsigned long long m2 = __ballot((t < 16) && (base1 + cum2 >= K));
      int M = (int)__ffsll(m2) - 1;
      unsigned base2 = __shfl(base1 + cum2 - v2, M, 64);
      int E = L * 16 + M;
      unsigned v3 = 0;
      if (t < 16) {
#pragma unroll
        for (int sl = 0; sl < kSLB; ++sl) v3 += ph_b[(size_t)sl * kBins + E * 16 + t];
      }
      unsigned cum3 = v3;
      for (int off = 1; off < 16; off <<= 1) {
        unsigned xx = __shfl_up(cum3, off, 64);
        if (t >= off) cum3 += xx;
      }
      unsigned long long m3 = __ballot((t < 16) && (base2 + cum3 >= K));
      int F = (int)__ffsll(m3) - 1;
      if (t == F) {
        s_bstar = E * 16 + F;
        s_need = (int)(K - (base2 + cum3 - v3));
      }
    }
    __syncthreads();
  }
  int bstar = s_bstar;
  int need = s_need;
  if (c == 0 && t == 0) { binfo[b * 2] = bstar; binfo[b * 2 + 1] = need; }

  // ---- os-CE slice + ordered candidate append ----
  const uint4* pz4_b = (const uint4*)(pz + (size_t)b * kNS);
  float ce_s = 0.0f, p_s = 0.0f, t_s = 0.0f, pt_s = 0.0f;
  unsigned meq = 0u;
  int lbase = 0;
  if (t < kSlice4) {
    int l4 = c * kSlice4 + t;
    uint4 u = pz4_b[l4];
    float4 tt4 = ((const float4*)(tv + (size_t)b * kNS))[l4];
    lbase = l4 * 4;
#pragma unroll
    for (int e = 0; e < 4; ++e) {
      unsigned ub = (e == 0) ? u.x : (e == 1) ? u.y : (e == 2) ? u.z : u.w;
      float ttv = (e == 0) ? tt4.x : (e == 1) ? tt4.y : (e == 2) ? tt4.z : tt4.w;
      int bin = (int)((ub & 0x7fffffffu) >> 17);
      float z = __uint_as_float(ub);
      float ce, p;
      ce_pair(z, ttv, ce, p);
      float w = (bin < bstar) ? 1.0f : 0.0f;
      ce_s += w * ce; p_s += w * p; t_s += w * ttv; pt_s += w * p * ttv;
      if (bin == bstar) meq |= 1u << e;
    }
  }
  unsigned cnt = __popc(meq);
  scan[t] = cnt;
  __syncthreads();
  for (int off = 1; off < 1024; off <<= 1) {
    unsigned v = (t >= off) ? scan[t - off] : 0u;
    __syncthreads();
    scan[t] += v;
    __syncthreads();
  }
  int pos = (int)(scan[t] - cnt);   // exclusive prefix -> index-ordered append
  int* cand_s = cand + ((size_t)b * kSLB + c) * kCAPS;
  unsigned mm = meq;
  while (mm) {
    int e = __ffs(mm) - 1;
    mm &= mm - 1;
    if (pos < kCAPS) cand_s[pos] = lbase + e;
    pos++;
  }
  if (t == 1023) scnt[b * kSLB + c] = (int)scan[1023];

  float vals[4] = {ce_s, p_s, t_s, pt_s};
#pragma unroll
  for (int q = 0; q < 4; ++q) {
    float v = vals[q];
    for (int o = 32; o > 0; o >>= 1) v += __shfl_down(v, o, 64);
    if ((t & 63) == 0) redf[(t >> 6) * 4 + q] = v;
  }
  __syncthreads();
  if (t == 0) {
    float o0 = 0, o1 = 0, o2 = 0, o3 = 0;
    for (int w = 0; w < 16; ++w) {
      o0 += redf[w * 4 + 0]; o1 += redf[w * 4 + 1];
      o2 += redf[w * 4 + 2]; o3 += redf[w * 4 + 3];
    }
    float* o = osp2 + ((size_t)b * kSLB + c) * 4;
    o[0] = o0; o[1] = o1; o[2] = o2; o[3] = o3;
  }
}

// ---- K4: 1 block: wave w handles batch w candidates (index order) + f64 finalize ----
__global__ __launch_bounds__(1024) void final_kernel(const unsigned* __restrict__ pz,
                                                     const float* __restrict__ tv,
                                                     const int* __restrict__ cand,
                                                     const int* __restrict__ scnt,
                                                     const int* __restrict__ binfo,
                                                     const float* __restrict__ osp2,
                                                     const float* __restrict__ plp,
                                                     const float* __restrict__ rgp,
                                                     float* __restrict__ out) {
  __shared__ float bsum[kB][4];
  __shared__ double shd[kB][4];
  int t = threadIdx.x;
  int w = t >> 6;        // wave index = batch
  int l = t & 63;        // lane

  {
    int b = w;
    int bstar = binfo[b * 2];
    int need = binfo[b * 2 + 1];
    const unsigned* pz_b = pz + (size_t)b * kNS;
    const float* tv_b = tv + (size_t)b * kNS;
    unsigned cnt = (l < kSLB) ? (unsigned)scnt[b * kSLB + l] : 0u;
    unsigned incl = cnt;
    for (int off = 1; off < 16; off <<= 1) {
      unsigned xx = __shfl_up(incl, off, 64);
      if (l >= off) incl += xx;
    }
    float ce_s = 0.0f, p_s = 0.0f, t_s = 0.0f, pt_s = 0.0f;
    for (int s = 0; s < kSLB; ++s) {
      int cnt_s = (int)__shfl(cnt, s, 64);
      int excl_s = (int)__shfl(incl, s, 64) - cnt_s;
      int take = min(cnt_s, max(0, need - excl_s));
      if (take <= 0) continue;
      if (cnt_s <= kCAPS) {
        const int* cand_s = cand + ((size_t)b * kSLB + s) * kCAPS;
        for (int i = l; i < take; i += 64) {
          int my = cand_s[i];
          float z = __uint_as_float(pz_b[my]);
          float ttv = tv_b[my];
          float ce, p;
          ce_pair(z, ttv, ce, p);
          ce_s += ce; p_s += p; t_s += ttv; pt_s += p * ttv;
        }
      } else {
        // overflow fallback: scan slice s in index order (deterministic)
        int base = 0;
        int start = s * (kSlice4 * 4);
        for (int r = 0; r < (kSlice4 * 4 + 63) / 64; ++r) {
          int idx = start + r * 64 + l;
          bool match = false;
          if (r * 64 + l < kSlice4 * 4) {
            unsigned ub = pz_b[idx];
            match = ((int)((ub & 0x7fffffffu) >> 17) == bstar);
          }
          unsigned long long mball = __ballot(match);
          int myrank = (int)__popcll(mball & ((1ull << l) - 1ull));
          if (match && base + myrank < take) {
            float z = __uint_as_float(pz_b[idx]);
            float ttv = tv_b[idx];
            float ce, p;
            ce_pair(z, ttv, ce, p);
            ce_s += ce; p_s += p; t_s += ttv; pt_s += p * ttv;
          }
          base += (int)__popcll(mball);
        }
      }
    }
    for (int o = 32; o > 0; o >>= 1) {
      ce_s += __shfl_down(ce_s, o, 64);
      p_s += __shfl_down(p_s, o, 64);
      t_s += __shfl_down(t_s, o, 64);
      pt_s += __shfl_down(pt_s, o, 64);
    }
    if (l == 0) { bsum[b][0] = ce_s; bsum[b][1] = p_s; bsum[b][2] = t_s; bsum[b][3] = pt_s; }
  }
  __syncthreads();

  if (t < kB) {
    double ce = bsum[t][0], p = bsum[t][1], tt = bsum[t][2], pt = bsum[t][3];
    for (int c = 0; c < kSLB; ++c) {
      const float* q = osp2 + ((size_t)t * kSLB + c) * 4;
      ce += q[0]; p += q[1]; tt += q[2]; pt += q[3];
    }
    for (int c = 0; c < kRPB; ++c) {
      const float* q = plp + ((size_t)t * kRPB + c) * 4;
      ce += q[0]; p += q[1]; tt += q[2]; pt += q[3];
    }
    double ws = 0, bc = 0, in = 0, pw = 0, gw = 0;
    for (int c = 0; c < kSLB; ++c) {
      const float* q = rgp + ((size_t)t * kSLB + c) * 5;
      ws += q[0]; bc += q[1]; in += q[2]; pw += q[3]; gw += q[4];
    }
    shd[t][0] = ce / (double)kNPTS;
    shd[t][1] = 1.0 - (2.0 * pt + 1.0) / (p + tt + 1.0);
    double wss = ws > 1e-6 ? ws : 1e-6;
    shd[t][2] = bc / wss;
    shd[t][3] = 1.0 - (2.0 * in + 1.0) / (pw + gw + 1.0);
  }
  __syncthreads();
  if (t == 0) {
    double a = 0, b2 = 0, c2 = 0, d = 0;
    for (int i = 0; i < kB; ++i) { a += shd[i][0]; b2 += shd[i][1]; c2 += shd[i][2]; d += shd[i][3]; }
    out[0] = (float)(a / 16.0);
    out[1] = (float)(b2 / 16.0);
    out[2] = (float)(c2 / 16.0);
    out[3] = (float)(d / 16.0);
  }
}

extern "C" void kernel_launch(void* const* d_in, const int* in_sizes, int n_in,
                              void* d_out, int out_size, void* d_ws, size_t ws_size,
                              hipStream_t stream) {
  const float* pred = (const float*)d_in[0];
  const float* gt = (const float*)d_in[1];
  const float* coords_os = (const float*)d_in[2];
  const float* coords_rand = (const float*)d_in[3];
  float* out = (float*)d_out;
  char* ws = (char*)d_ws;

  unsigned* pz = (unsigned*)(ws + OFF_PZ);
  float* tv = (float*)(ws + OFF_TV);
  unsigned short* ph = (unsigned short*)(ws + OFF_PH);
  int* bbp = (int*)(ws + OFF_BBP);
  float* plp = (float*)(ws + OFF_PLP);
  float* osp2 = (float*)(ws + OFF_OSP2);
  float* rgp = (float*)(ws + OFF_RGP);
  int* cand = (int*)(ws + OFF_CAND);
  int* scnt = (int*)(ws + OFF_SCNT);
  int* binfo = (int*)(ws + OFF_BNFO);

  fused1_kernel<<<kSampleBlocks + kBboxBlocks + kRandBlocks, 256, 0, stream>>>(
      pred, gt, coords_os, coords_rand, pz, tv, bbp, plp);
  region_hist_kernel<<<kB * kSLB, 1024, 0, stream>>>(pz, pred, gt, bbp, rgp, ph);
  combine_osce_kernel<<<kB * kSLB, 1024, 0, stream>>>(pz, tv, ph, osp2, cand, scnt, binfo);
  final_kernel<<<1, 1024, 0, stream>>>(pz, tv, cand, scnt, binfo, osp2, plp, rgp, out);
}

// Round 16
// 69.054 us; speedup vs baseline: 1.6072x; 1.6072x over previous
//
#include <hip/hip_runtime.h>
#include <cstdint>
#include <cstddef>

namespace {

constexpr int kB = 16;
constexpr int kH = 512;
constexpr int kW = 512;
constexpr int kHW = kH * kW;
constexpr int kNS = 37632;     // NUM_POINTS * OVERSAMPLE
constexpr int kNS4 = kNS / 4;  // 9408
constexpr int kNUNC = 9408;
constexpr int kNRAND = 3136;
constexpr int kNPTS = 12544;
constexpr int kBXB = 16;       // bbox partial blocks per batch
constexpr int kRPB = 4;        // rand-point blocks per batch
constexpr int kRGB2 = 16;      // region blocks per batch (1024 threads each)
constexpr int kPairs = kNS / 2;                  // 18816 pairs per batch
constexpr int kSampSlots = 148;                  // slots per XCD (2 batches x 74 chunks)
constexpr int kSampleBlocks = 8 * kSampSlots;    // 1184
constexpr int kBboxBlocks = kB * kBXB;           // 256
constexpr int kRandBlocks = kB * kRPB;           // 64

constexpr int kBins = 2048;        // |z| bins: exp(8) + mant(3)  (bits >> 20)
constexpr int kHRows = 8;          // wave-pair private sub-histograms
constexpr int kHRow = kBins + 8;   // 2056 words: stagger row starts across banks
constexpr int kCAP = 2048;         // boundary-bin candidate capacity

// workspace layout (bytes) — identical to round 9
constexpr size_t OFF_PU  = 0;                                     // [B][NS] u32  |z| bits
constexpr size_t OFF_TRM = OFF_PU + (size_t)kB * kNS * 4;         // [B][NS] float4 (ce,p,t,pt)
constexpr size_t OFF_BBP = OFF_TRM + (size_t)kB * kNS * 16;       // [B][16][4] i32
constexpr size_t OFF_PLP = OFF_BBP + (size_t)kB * kBXB * 4 * 4;   // [B][4][4] f32 rand partials
constexpr size_t OFF_OSP = OFF_PLP + (size_t)kB * kRPB * 4 * 4;   // [B][4] f32 os sums
constexpr size_t OFF_RGP = OFF_OSP + (size_t)kB * 4 * 4;          // [B][16][5] f32 region partials

} // namespace

__device__ __forceinline__ float sample_bilinear(const float* __restrict__ img,
                                                 float cx, float cy) {
  float x = cx * (float)kW - 0.5f;
  float y = cy * (float)kH - 0.5f;
  float x0f = floorf(x), y0f = floorf(y);
  float wx1 = x - x0f, wx0 = 1.0f - wx1;
  float wy1 = y - y0f, wy0 = 1.0f - wy1;
  int x0 = (int)x0f, y0 = (int)y0f;
  int x1 = x0 + 1, y1 = y0 + 1;
  int xc0 = min(max(x0, 0), kW - 1), xc1 = min(max(x1, 0), kW - 1);
  int yc0 = min(max(y0, 0), kH - 1), yc1 = min(max(y1, 0), kH - 1);
  float v00 = ((x0 >= 0) && (x0 < kW) && (y0 >= 0) && (y0 < kH)) ? img[yc0 * kW + xc0] : 0.0f;
  float v01 = ((x1 >= 0) && (x1 < kW) && (y0 >= 0) && (y0 < kH)) ? img[yc0 * kW + xc1] : 0.0f;
  float v10 = ((x0 >= 0) && (x0 < kW) && (y1 >= 0) && (y1 < kH)) ? img[yc1 * kW + xc0] : 0.0f;
  float v11 = ((x1 >= 0) && (x1 < kW) && (y1 >= 0) && (y1 < kH)) ? img[yc1 * kW + xc1] : 0.0f;
  return v00 * (wy0 * wx0) + v01 * (wy0 * wx1) + v10 * (wy1 * wx0) + v11 * (wy1 * wx1);
}

__device__ __forceinline__ void ce_pair(float z, float tt, float& ce, float& p) {
  float a = expf(-fabsf(z));
  ce = fmaxf(z, 0.0f) - z * tt + log1pf(a);
  float inv = 1.0f / (1.0f + a);
  p = (z >= 0.0f) ? inv : a * inv;
}

// ---- K1: os sampling+CE terms | bbox partials | rand CE partials; XCD-clustered ----
__global__ __launch_bounds__(256) void fused1_kernel(const float* __restrict__ pred,
                                                     const float* __restrict__ gt,
                                                     const float* __restrict__ coords_os,
                                                     const float* __restrict__ coords_rand,
                                                     unsigned* __restrict__ pu,
                                                     float4* __restrict__ trm,
                                                     int* __restrict__ bbp,
                                                     float* __restrict__ plp) {
  int blk = blockIdx.x;
  int t = threadIdx.x;

  if (blk < kSampleBlocks) {
    int x = blk & 7;
    int s = blk >> 3;                 // 0..147
    int b = x * 2 + (s & 1);          // XCD-clustered: batch b on XCD b/2
    int chunk = s >> 1;               // 0..73
    int pib = chunk * 256 + t;
    if (pib >= kPairs) return;
    size_t gp = (size_t)b * kPairs + pib;
    float4 c2 = ((const float4*)coords_os)[gp];
    size_t i0 = gp * 2;
    const float* pred_b = pred + (size_t)b * kHW;
    const float* gt_b = gt + (size_t)b * kHW;
    float z0 = sample_bilinear(pred_b, c2.x, c2.y);
    float z1 = sample_bilinear(pred_b, c2.z, c2.w);
    float t0 = sample_bilinear(gt_b, c2.x, c2.y);
    float t1 = sample_bilinear(gt_b, c2.z, c2.w);
    float ce0, p0, ce1, p1;
    ce_pair(z0, t0, ce0, p0);
    ce_pair(z1, t1, ce1, p1);
    unsigned u0 = __float_as_uint(z0) & 0x7fffffffu;
    unsigned u1 = __float_as_uint(z1) & 0x7fffffffu;
    *(uint2*)&pu[i0] = make_uint2(u0, u1);
    trm[i0] = make_float4(ce0, p0, t0, p0 * t0);
    trm[i0 + 1] = make_float4(ce1, p1, t1, p1 * t1);
    return;
  }

  if (blk < kSampleBlocks + kBboxBlocks) {
    __shared__ int r0[256], r1[256], r2[256], r3[256];
    int i = blk - kSampleBlocks;
    int x = i & 7;
    int s = i >> 3;                   // 0..31
    int b = x * 2 + (s & 1);
    int c = s >> 1;                   // 0..15
    constexpr int CHUNK4 = kHW / kBXB / 4;  // 4096 float4
    const float4* pred4 = (const float4*)(pred + (size_t)b * kHW) + (size_t)c * CHUNK4;
    int pbase = c * CHUNK4 * 4;
    int xmn = kW, xmx = -1, ymn = kH, ymx = -1;
    for (int i4 = t; i4 < CHUNK4; i4 += 256) {
      float4 z = pred4[i4];
      int p = pbase + i4 * 4;
      int y = p >> 9;
      int x0 = p & (kW - 1);
      if (z.x > 0.0f) { xmn = min(xmn, x0);     xmx = max(xmx, x0);     ymn = min(ymn, y); ymx = max(ymx, y); }
      if (z.y > 0.0f) { xmn = min(xmn, x0 + 1); xmx = max(xmx, x0 + 1); ymn = min(ymn, y); ymx = max(ymx, y); }
      if (z.z > 0.0f) { xmn = min(xmn, x0 + 2); xmx = max(xmx, x0 + 2); ymn = min(ymn, y); ymx = max(ymx, y); }
      if (z.w > 0.0f) { xmn = min(xmn, x0 + 3); xmx = max(xmx, x0 + 3); ymn = min(ymn, y); ymx = max(ymx, y); }
    }
    r0[t] = xmn; r1[t] = xmx; r2[t] = ymn; r3[t] = ymx;
    __syncthreads();
    for (int s2 = 128; s2 > 0; s2 >>= 1) {
      if (t < s2) {
        r0[t] = min(r0[t], r0[t + s2]);
        r1[t] = max(r1[t], r1[t + s2]);
        r2[t] = min(r2[t], r2[t + s2]);
        r3[t] = max(r3[t], r3[t + s2]);
      }
      __syncthreads();
    }
    if (t == 0) {
      int* o = bbp + ((size_t)b * kBXB + c) * 4;
      o[0] = r0[0]; o[1] = r1[0]; o[2] = r2[0]; o[3] = r3[0];
    }
    return;
  }

  // rand-point CE partials
  {
    __shared__ float red[4][256];
    int i = blk - kSampleBlocks - kBboxBlocks;
    int x = i & 7;
    int s = i >> 3;                   // 0..7
    int b = x * 2 + (s & 1);
    int c = s >> 1;                   // 0..3
    const float* pred_b = pred + (size_t)b * kHW;
    const float* gt_b = gt + (size_t)b * kHW;
    float ce_s = 0.0f, p_s = 0.0f, t_s = 0.0f, pt_s = 0.0f;
    for (int e = c * 256 + t; e < kNRAND; e += kRPB * 256) {
      float2 cc = *(const float2*)&coords_rand[((size_t)b * kNRAND + e) * 2];
      float z = sample_bilinear(pred_b, cc.x, cc.y);
      float tt = sample_bilinear(gt_b, cc.x, cc.y);
      float ce, p;
      ce_pair(z, tt, ce, p);
      ce_s += ce; p_s += p; t_s += tt; pt_s += p * tt;
    }
    red[0][t] = ce_s; red[1][t] = p_s; red[2][t] = t_s; red[3][t] = pt_s;
    __syncthreads();
    for (int s2 = 128; s2 > 0; s2 >>= 1) {
      if (t < s2) {
        red[0][t] += red[0][t + s2];
        red[1][t] += red[1][t + s2];
        red[2][t] += red[2][t + s2];
        red[3][t] += red[3][t + s2];
      }
      __syncthreads();
    }
    if (t == 0) {
      float* o = plp + ((size_t)b * kRPB + c) * 4;
      o[0] = red[0][0]; o[1] = red[1][0]; o[2] = red[2][0]; o[3] = red[3][0];
    }
  }
}

// ---- K2: select+CE-sum (blocks 0..15) | region (blocks 16..271) ----
// Select hist: 8 wave-pair-private 2048-bin LDS sub-hists (contention / 8),
// combined + scanned in-block. LDS total 78 KB -> 2 blocks/CU (same as r9).
__global__ __launch_bounds__(1024) void fused2_kernel(const unsigned* __restrict__ pu,
                                                      const float4* __restrict__ trm,
                                                      const float* __restrict__ pred,
                                                      const float* __restrict__ gt,
                                                      const int* __restrict__ bbp,
                                                      float* __restrict__ osp,
                                                      float* __restrict__ rgp) {
  __shared__ unsigned smem[kHRows * kHRow + kCAP + 1024];  // hist | cand | sums (78 KB)
  __shared__ int s_bstar, s_need, s_ccnt, s_round;
  int blk = blockIdx.x;
  int t = threadIdx.x;

  if (blk < kB) {
    constexpr int C4 = 10;           // ceil(9408/1024)
    int b = (blk & 7) * 2 + (blk >> 3);   // batch b on XCD b/2 (matches K1 residue)
    const uint4* pu4_b = (const uint4*)(pu + (size_t)b * kNS);
    const float4* trm_b = trm + (size_t)b * kNS;
    unsigned* hist = smem;                          // 8 x 2056
    int* cand = (int*)(smem + kHRows * kHRow);      // 2048
    unsigned* sums = smem + kHRows * kHRow + kCAP;  // 1024

    for (int i = t; i < kHRows * kHRow; i += 1024) hist[i] = 0u;
    if (t == 0) s_ccnt = 0;
    __syncthreads();

    // pass 1: wave-pair-private histogram (bin = |z|bits >> 20, 2048 bins)
    unsigned* myh = hist + (t >> 7) * kHRow;
#pragma unroll 2
    for (int j = 0; j < C4; ++j) {
      int idx4 = j * 1024 + t;
      if (idx4 < kNS4) {
        uint4 u = pu4_b[idx4];
        atomicAdd(&myh[u.x >> 20], 1u);
        atomicAdd(&myh[u.y >> 20], 1u);
        atomicAdd(&myh[u.z >> 20], 1u);
        atomicAdd(&myh[u.w >> 20], 1u);
      }
    }
    __syncthreads();

    // combine rows into row 0 (each bin owned by one thread: t and t+1024)
    for (int bin = t; bin < kBins; bin += 1024) {
      unsigned f = 0;
#pragma unroll
      for (int w = 0; w < kHRows; ++w) f += hist[w * kHRow + bin];
      hist[bin] = f;                 // row 0 = full hist
    }
    __syncthreads();

    // boundary search: pair-sums -> 64-supergroup shfl scan -> 16-entry scan -> 2 bins
    sums[t] = hist[2 * t] + hist[2 * t + 1];
    __syncthreads();
    if (t < 64) {
      const unsigned K = (unsigned)kNUNC;
      unsigned v = 0;
#pragma unroll
      for (int k = 0; k < 16; ++k) v += sums[t * 16 + k];   // 32 bins each
      unsigned cum = v;
      for (int off = 1; off < 64; off <<= 1) {
        unsigned xx = __shfl_up(cum, off, 64);
        if (t >= off) cum += xx;
      }
      unsigned long long m = __ballot(cum >= K);
      int L = (int)__ffsll(m) - 1;
      unsigned base1 = __shfl(cum - v, L, 64);
      unsigned v2 = (t < 16) ? sums[L * 16 + t] : 0u;
      unsigned cum2 = v2;
      for (int off = 1; off < 16; off <<= 1) {
        unsigned xx = __shfl_up(cum2, off, 64);
        if (t >= off) cum2 += xx;
      }
      unsigned long long m2 = __ballot((t < 16) && (base1 + cum2 >= K));
      int M = (int)__ffsll(m2) - 1;
      unsigned base2 = __shfl(base1 + cum2 - v2, M, 64);
      int E = L * 16 + M;            // pair-entry: bins 2E, 2E+1
      if (t == 0) {
        unsigned c0 = hist[2 * E];
        if (base2 + c0 >= K) { s_bstar = 2 * E;     s_need = (int)(K - base2); }
        else                 { s_bstar = 2 * E + 1; s_need = (int)(K - base2 - c0); }
      }
    }
    __syncthreads();
    int bstar = s_bstar;
    int need = s_need;

    // pass 2: re-load pu (L2-hot) + unconditional float4 trm stream, branchless
    float ce_s = 0.0f, p_s = 0.0f, t_s = 0.0f, pt_s = 0.0f;
#pragma unroll 2
    for (int j = 0; j < C4; ++j) {
      int idx4 = j * 1024 + t;
      if (idx4 < kNS4) {
        uint4 u = pu4_b[idx4];
        const float4* base = trm_b + (size_t)idx4 * 4;
        float4 q0 = base[0];
        float4 q1 = base[1];
        float4 q2 = base[2];
        float4 q3 = base[3];
        int b0 = (int)(u.x >> 20), b1 = (int)(u.y >> 20);
        int b2 = (int)(u.z >> 20), b3 = (int)(u.w >> 20);
        float w0 = (b0 < bstar) ? 1.0f : 0.0f;
        float w1 = (b1 < bstar) ? 1.0f : 0.0f;
        float w2 = (b2 < bstar) ? 1.0f : 0.0f;
        float w3 = (b3 < bstar) ? 1.0f : 0.0f;
        ce_s += w0 * q0.x + w1 * q1.x + w2 * q2.x + w3 * q3.x;
        p_s  += w0 * q0.y + w1 * q1.y + w2 * q2.y + w3 * q3.y;
        t_s  += w0 * q0.z + w1 * q1.z + w2 * q2.z + w3 * q3.z;
        pt_s += w0 * q0.w + w1 * q1.w + w2 * q2.w + w3 * q3.w;
        if (b0 == bstar) { int pos = atomicAdd(&s_ccnt, 1); if (pos < kCAP) cand[pos] = idx4 * 4 + 0; }
        if (b1 == bstar) { int pos = atomicAdd(&s_ccnt, 1); if (pos < kCAP) cand[pos] = idx4 * 4 + 1; }
        if (b2 == bstar) { int pos = atomicAdd(&s_ccnt, 1); if (pos < kCAP) cand[pos] = idx4 * 4 + 2; }
        if (b3 == bstar) { int pos = atomicAdd(&s_ccnt, 1); if (pos < kCAP) cand[pos] = idx4 * 4 + 3; }
      }
    }
    __syncthreads();
    int c = s_ccnt;

    if (c <= kCAP) {
      for (int i = t; i < c; i += 1024) {
        int my = cand[i];
        int r = 0;
        for (int k = 0; k < c; ++k) r += (cand[k] < my) ? 1 : 0;
        if (r < need) {
          float4 q = trm_b[my];
          ce_s += q.x; p_s += q.y; t_s += q.z; pt_s += q.w;
        }
      }
      __syncthreads();
    } else {
      // ordered-scan fallback (pathological duplicate-heavy data)
      if (t == 0) s_round = 0;
      __syncthreads();
      for (int j = 0; j < C4; ++j) {
        int idx4 = j * 1024 + t;
        unsigned meq = 0u;
        if (idx4 < kNS4) {
          uint4 u = pu4_b[idx4];
          meq = (unsigned)((int)(u.x >> 20) == bstar) |
                ((unsigned)((int)(u.y >> 20) == bstar) << 1) |
                ((unsigned)((int)(u.z >> 20) == bstar) << 2) |
                ((unsigned)((int)(u.w >> 20) == bstar) << 3);
        }
        unsigned cnt2 = __popc(meq);
        sums[t] = cnt2;
        __syncthreads();
        for (int off = 1; off < 1024; off <<= 1) {
          unsigned v = (t >= off) ? sums[t - off] : 0u;
          __syncthreads();
          sums[t] += v;
          __syncthreads();
        }
        int myBase = s_round + (int)(sums[t] - cnt2);
        unsigned mm = meq;
        while (mm) {
          int e = __ffs(mm) - 1;
          mm &= mm - 1;
          if (myBase < need) {
            float4 q = trm_b[idx4 * 4 + e];
            ce_s += q.x; p_s += q.y; t_s += q.z; pt_s += q.w;
          }
          myBase++;
        }
        __syncthreads();
        if (t == 0) s_round += (int)sums[1023];
        __syncthreads();
      }
    }

    // reduce 4 sums: per-wave shfl -> 16 wave partials -> thread 0
    float* redf = (float*)sums;
    float vals[4] = {ce_s, p_s, t_s, pt_s};
#pragma unroll
    for (int q = 0; q < 4; ++q) {
      float v = vals[q];
      for (int o = 32; o > 0; o >>= 1) v += __shfl_down(v, o, 64);
      if ((t & 63) == 0) redf[(t >> 6) * 4 + q] = v;
    }
    __syncthreads();
    if (t == 0) {
      float o0 = 0, o1 = 0, o2 = 0, o3 = 0;
      for (int w = 0; w < 16; ++w) {
        o0 += redf[w * 4 + 0]; o1 += redf[w * 4 + 1];
        o2 += redf[w * 4 + 2]; o3 += redf[w * 4 + 3];
      }
      float* o = osp + (size_t)b * 4;
      o[0] = o0; o[1] = o1; o[2] = o2; o[3] = o3;
    }
    return;
  }

  // region portion (1024 threads/block), XCD-clustered: batch b on XCD b/2
  {
    constexpr int CHUNK4 = kHW / kRGB2 / 4;  // 4096 float4 per block
    int i = blk - kB;
    int x = i & 7;
    int s = i >> 3;                   // 0..31
    int b = x * 2 + (s & 1);
    int c = s >> 1;                   // 0..15
    const float4* pred4 = (const float4*)(pred + (size_t)b * kHW) + (size_t)c * CHUNK4;
    const float4* gt4 = (const float4*)(gt + (size_t)b * kHW) + (size_t)c * CHUNK4;

    int xmn = kW, xmx = -1, ymn = kH, ymx = -1;
#pragma unroll
    for (int u = 0; u < kBXB; ++u) {
      const int4 pb = *(const int4*)(bbp + ((size_t)b * kBXB + u) * 4);
      xmn = min(xmn, pb.x); xmx = max(xmx, pb.y);
      ymn = min(ymn, pb.z); ymx = max(ymx, pb.w);
    }
    bool empty = (xmx < 0);
    int x1 = empty ? 0 : xmn;
    int x2 = min(empty ? (kW - 1) : xmx, kW - 1);
    int y1 = empty ? 0 : ymn;
    int y2 = min(empty ? (kH - 1) : ymx, kH - 1);
    bool valid = (x2 > x1) && (y2 > y1);

    int pbase = c * CHUNK4 * 4;
    float wsum = 0.0f, bcew = 0.0f, inter = 0.0f, pw = 0.0f, gw = 0.0f;
    for (int i4 = t; i4 < CHUNK4; i4 += 1024) {
      float4 zv = pred4[i4];
      float4 gv = gt4[i4];
      int p = pbase + i4 * 4;
      int y = p >> 9;
      int x0 = p & (kW - 1);
      bool iny = valid && (y >= y1) && (y <= y2);
#pragma unroll
      for (int l = 0; l < 4; ++l) {
        float z = (l == 0) ? zv.x : (l == 1) ? zv.y : (l == 2) ? zv.z : zv.w;
        float g = (l == 0) ? gv.x : (l == 1) ? gv.y : (l == 2) ? gv.z : gv.w;
        int xx = x0 + l;
        float w = (iny && xx >= x1 && xx <= x2) ? 2.0f : 0.5f;
        float a = expf(-fabsf(z));
        float sp = fmaxf(-z, 0.0f) + log1pf(a);   // softplus(-z) = -log_sigmoid(z)
        float bce = sp + (1.0f - g) * z;
        float inv = 1.0f / (1.0f + a);
        float pp = (z >= 0.0f) ? inv : a * inv;
        wsum += w;
        bcew += bce * w;
        inter += pp * g * w;
        pw += pp * w;
        gw += g * w;
      }
    }
    float* redf = (float*)smem;
    float vals[5] = {wsum, bcew, inter, pw, gw};
#pragma unroll
    for (int q5 = 0; q5 < 5; ++q5) {
      float v = vals[q5];
      for (int o = 32; o > 0; o >>= 1) v += __shfl_down(v, o, 64);
      if ((t & 63) == 0) redf[(t >> 6) * 5 + q5] = v;
    }
    __syncthreads();
    if (t == 0) {
      float o0 = 0, o1 = 0, o2 = 0, o3 = 0, o4 = 0;
      for (int w = 0; w < 16; ++w) {
        o0 += redf[w * 5 + 0]; o1 += redf[w * 5 + 1]; o2 += redf[w * 5 + 2];
        o3 += redf[w * 5 + 3]; o4 += redf[w * 5 + 4];
      }
      float* o = rgp + ((size_t)b * kRGB2 + c) * 5;
      o[0] = o0; o[1] = o1; o[2] = o2; o[3] = o3; o[4] = o4;
    }
  }
}

// ---- K3: finalize in f64 ----
__global__ __launch_bounds__(64) void finalize_kernel(const float* __restrict__ plp,
                                                      const float* __restrict__ osp,
                                                      const float* __restrict__ rgp,
                                                      float* __restrict__ out) {
  __shared__ double sh[kB][4];
  int t = threadIdx.x;
  if (t < kB) {
    const float* o = osp + (size_t)t * 4;
    double ce = o[0], p = o[1], tt = o[2], pt = o[3];
    for (int c = 0; c < kRPB; ++c) {
      const float* q = plp + ((size_t)t * kRPB + c) * 4;
      ce += q[0]; p += q[1]; tt += q[2]; pt += q[3];
    }
    double ws = 0, bc = 0, in = 0, pw = 0, gw = 0;
    for (int c = 0; c < kRGB2; ++c) {
      const float* q = rgp + ((size_t)t * kRGB2 + c) * 5;
      ws += q[0]; bc += q[1]; in += q[2]; pw += q[3]; gw += q[4];
    }
    sh[t][0] = ce / (double)kNPTS;
    sh[t][1] = 1.0 - (2.0 * pt + 1.0) / (p + tt + 1.0);
    double wss = ws > 1e-6 ? ws : 1e-6;
    sh[t][2] = bc / wss;
    sh[t][3] = 1.0 - (2.0 * in + 1.0) / (pw + gw + 1.0);
  }
  __syncthreads();
  if (t == 0) {
    double a = 0, b = 0, c = 0, d = 0;
    for (int i = 0; i < kB; ++i) { a += sh[i][0]; b += sh[i][1]; c += sh[i][2]; d += sh[i][3]; }
    out[0] = (float)(a / 16.0);
    out[1] = (float)(b / 16.0);
    out[2] = (float)(c / 16.0);
    out[3] = (float)(d / 16.0);
  }
}

extern "C" void kernel_launch(void* const* d_in, const int* in_sizes, int n_in,
                              void* d_out, int out_size, void* d_ws, size_t ws_size,
                              hipStream_t stream) {
  const float* pred = (const float*)d_in[0];
  const float* gt = (const float*)d_in[1];
  const float* coords_os = (const float*)d_in[2];
  const float* coords_rand = (const float*)d_in[3];
  float* out = (float*)d_out;
  char* ws = (char*)d_ws;

  unsigned* pu = (unsigned*)(ws + OFF_PU);
  float4* trm = (float4*)(ws + OFF_TRM);
  int* bbp = (int*)(ws + OFF_BBP);
  float* plp = (float*)(ws + OFF_PLP);
  float* osp = (float*)(ws + OFF_OSP);
  float* rgp = (float*)(ws + OFF_RGP);

  fused1_kernel<<<kSampleBlocks + kBboxBlocks + kRandBlocks, 256, 0, stream>>>(
      pred, gt, coords_os, coords_rand, pu, trm, bbp, plp);
  fused2_kernel<<<kB + kB * kRGB2, 1024, 0, stream>>>(pu, trm, pred, gt, bbp, osp, rgp);
  finalize_kernel<<<1, 64, 0, stream>>>(plp, osp, rgp, out);
}